// Round 6
// baseline (14.470 us; speedup 1.0000x reference)
//
#include <hip/hip_runtime.h>

// Problem constants
#define D1 128
#define D2 128
#define XC 64
#define NBH 16              // batches per block (32 total / 2 halves)
#define RS 16               // LDS row stride (pow2)
#define RR 12               // region edge: 8 (tile) + 4 (halo)
#define BSTR (RR * RS)      // 192 floats per batch plane
#define B1 (NBH * BSTR)     // 3072: ping-pong buffer offset
#define NTH 192
#define PLANE 16384         // floats per gate combo plane (128*128)

typedef float v2f __attribute__((ext_vector_type(2)));

__device__ __forceinline__ float fast_sigmoid(float v) {
    return __builtin_amdgcn_rcpf(1.0f + __expf(-v));   // |rel err| ~1e-7, fine vs 1.4e-2
}
__device__ __forceinline__ v2f clamp01v(v2f r) {
    r = __builtin_elementwise_max(r, (v2f)0.0f);
    return __builtin_elementwise_min(r, (v2f)1.0f);
}

// Full 16-gate multilinear interp layer, 2 batches per iteration (packed f32).
// Gates g / deltas d are batch-invariant scalars -> splat into v_pk operands.
__device__ __forceinline__ void compute_layer(float* __restrict__ st, int src, int dst,
                                              int sbase, const float g[16]) {
    float d[8];
#pragma unroll
    for (int k = 0; k < 8; ++k) d[k] = g[2 * k + 1] - g[2 * k];
#pragma unroll
    for (int b = 0; b < NBH; b += 2) {
        const float* s0 = st + src + b * BSTR + sbase;
        const float* s1 = s0 + BSTR;
        const v2f f0 = {s0[0],  s1[0]};
        const v2f f1 = {s0[1],  s1[1]};
        const v2f f2 = {s0[RS], s1[RS]};
        const v2f f3 = {s0[RS + 1], s1[RS + 1]};
        v2f u[8];
#pragma unroll
        for (int k = 0; k < 8; ++k) u[k] = f3 * d[k] + g[2 * k];
        v2f v[4];
#pragma unroll
        for (int k = 0; k < 4; ++k) v[k] = f2 * (u[2 * k + 1] - u[2 * k]) + u[2 * k];
        v2f w[2];
#pragma unroll
        for (int k = 0; k < 2; ++k) w[k] = f1 * (v[2 * k + 1] - v[2 * k]) + v[2 * k];
        const v2f r = clamp01v(f0 * (w[1] - w[0]) + w[0]);
        st[dst + b * BSTR + sbase]       = r.x;
        st[dst + (b + 1) * BSTR + sbase] = r.y;
    }
}

__global__ __launch_bounds__(NTH) void fused_kernel(const float* __restrict__ x,
                                                    const float* __restrict__ tg,
                                                    float* __restrict__ out) {
    __shared__ float st[2 * B1 + 64];    // ping-pong state + pad for harmless edge reads

    const int tid  = threadIdx.x;
    const int tile = blockIdx.x & 255;
    const int b0   = (blockIdx.x >> 8) * NBH;    // batch offset of this half

    const int q1 = tid >> 4;             // 0..11
    const int q2 = tid & 15;             // 0..15
    const bool act = (q2 < RR);

    const int t1 = ((tile >> 4) & 15) << 3;
    const int t2 = (tile & 15) << 3;
    const int p1  = (t1 + q1) & (D1 - 1);
    const int p2  = (t2 + q2) & (D2 - 1);
    const int p1n = (p1 + 1) & (D1 - 1);
    const int p2n = (p2 + 1) & (D2 - 1);
    const int sbase = (q1 << 4) | q2;
    const int modd = p2 & 1;             // == q2&1 since t2 is even
    const float* gcell = tg + (p1 << 7) + p2;

    // ---- gate loads for layers 0 and 1 issued up front ----
    float g0[4], graw[16];
    if (act) {
        // layer-0 gates: parity-reduced bilerp needs only 4 of 16 combos
        // even p2 (f1=f3=0): m in {0,2,8,10};  odd p2 (f0=f2=0): m in {0,1,4,5}
#pragma unroll
        for (int j = 0; j < 4; ++j) {
            const int m = modd ? ((j >> 1) * 4 + (j & 1)) : ((j >> 1) * 8 + (j & 1) * 2);
            g0[j] = gcell[(size_t)m * PLANE];
        }
#pragma unroll
        for (int m = 0; m < 16; ++m) graw[m] = gcell[(size_t)(16 + m) * PLANE];
    }

    // ---- layer 0: read x DIRECTLY (no staging barrier) -> st[B1], packed pairs ----
    // even cell: inner lerp over f2 = x[p1n][c], outer over f0 = x[p1][c]
    // odd  cell: inner lerp over f3 = x[p1n][c], outer over f1 = x[p1][c]
    if (act) {
#pragma unroll
        for (int j = 0; j < 4; ++j) g0[j] = fast_sigmoid(g0[j]);
        const float d10 = g0[1] - g0[0], d32 = g0[3] - g0[2];
        const int c = (modd ? p2n : p2) >> 1;
        const float* xo = x + ((size_t)b0 * D1 + p1)  * XC + c;   // outer tap
        const float* xi = x + ((size_t)b0 * D1 + p1n) * XC + c;   // inner tap
#pragma unroll
        for (int b = 0; b < NBH; b += 2) {
            const v2f fout = {xo[(size_t)b * (D1 * XC)], xo[(size_t)(b + 1) * (D1 * XC)]};
            const v2f fin  = {xi[(size_t)b * (D1 * XC)], xi[(size_t)(b + 1) * (D1 * XC)]};
            const v2f a_ = fin * d10 + g0[0];
            const v2f c_ = fin * d32 + g0[2];
            const v2f r  = clamp01v(fout * (c_ - a_) + a_);
            st[B1 + b * BSTR + sbase]       = r.x;
            st[B1 + (b + 1) * BSTR + sbase] = r.y;
        }
    }
    __syncthreads();

    // ---- layer 1: st[B1] -> st[0]; prefetch layer-2 gates ----
    float g[16], graw2[16];
    if (act) {
#pragma unroll
        for (int m = 0; m < 16; ++m) graw2[m] = gcell[(size_t)(32 + m) * PLANE];
#pragma unroll
        for (int m = 0; m < 16; ++m) g[m] = fast_sigmoid(graw[m]);
        compute_layer(st, B1, 0, sbase, g);
    }
    __syncthreads();

    // ---- tail mapping: 32 cells x 4 batch-groups over 128 threads ----
    const int c1 = (tid >> 2) & 7;       // tail cell row 0..7
    const int c2 = tid & 3;              // tail even-col index 0..3
    const int bh = tid >> 5;             // batch group 0..3 (tid<128)
    const int p1c = t1 + c1;             // no wrap needed
    const int p2c = t2 + (c2 << 1);
    const float* gcell3 = tg + (size_t)48 * PLANE + (p1c << 7) + p2c;

    // ---- layer 2: st[0] -> st[B1]; prefetch layer-3 gates for tail cell ----
    float graw3[16];
    if (tid < 128) {
#pragma unroll
        for (int m = 0; m < 16; ++m) graw3[m] = gcell3[(size_t)m * PLANE];
    }
    if (act) {
#pragma unroll
        for (int m = 0; m < 16; ++m) g[m] = fast_sigmoid(graw2[m]);
        compute_layer(st, 0, B1, sbase, g);
    }
    __syncthreads();

    // ---- layer 3: 128 threads x 1 cell x 4 batches (packed pairs) -> out ----
    if (tid < 128) {
#pragma unroll
        for (int m = 0; m < 16; ++m) g[m] = fast_sigmoid(graw3[m]);
        float d[8];
#pragma unroll
        for (int k = 0; k < 8; ++k) d[k] = g[2 * k + 1] - g[2 * k];
        const int sb3 = (c1 << 4) | (c2 << 1);
        float* op = out + ((size_t)(b0 + bh * 4) * D1 + p1c) * XC + (p2c >> 1);
#pragma unroll
        for (int b = 0; b < 4; b += 2) {
            const float* s0 = st + B1 + (bh * 4 + b) * BSTR + sb3;
            const float* s1 = s0 + BSTR;
            const v2f f0 = {s0[0],  s1[0]};
            const v2f f1 = {s0[1],  s1[1]};
            const v2f f2 = {s0[RS], s1[RS]};
            const v2f f3 = {s0[RS + 1], s1[RS + 1]};
            v2f u[8];
#pragma unroll
            for (int k = 0; k < 8; ++k) u[k] = f3 * d[k] + g[2 * k];
            v2f v[4];
#pragma unroll
            for (int k = 0; k < 4; ++k) v[k] = f2 * (u[2 * k + 1] - u[2 * k]) + u[2 * k];
            v2f w[2];
#pragma unroll
            for (int k = 0; k < 2; ++k) w[k] = f1 * (v[2 * k + 1] - v[2 * k]) + v[2 * k];
            const v2f r = clamp01v(f0 * (w[1] - w[0]) + w[0]);
            op[(size_t)b * (D1 * XC)]       = r.x;
            op[(size_t)(b + 1) * (D1 * XC)] = r.y;
        }
    }
}

extern "C" void kernel_launch(void* const* d_in, const int* in_sizes, int n_in,
                              void* d_out, int out_size, void* d_ws, size_t ws_size,
                              hipStream_t stream) {
    const float* x  = (const float*)d_in[0];   // (32,128,64)
    const float* tg = (const float*)d_in[1];   // (4,16,128,128)
    float* out = (float*)d_out;                // (32,128,64)

    fused_kernel<<<512, NTH, 0, stream>>>(x, tg, out);
}

// Round 7
// 14.059 us; speedup vs baseline: 1.0292x; 1.0292x over previous
//
#include <hip/hip_runtime.h>

// Problem constants
#define D1 128
#define D2 128
#define XC 64
#define NBH 16              // batches per block (32 total / 2 halves)
#define RS 16               // LDS row stride (pow2)
#define RR 12               // region edge: 8 (tile) + 4 (halo)
#define BSTR (RR * RS)      // 192 floats per batch plane
#define B1 (NBH * BSTR)     // 3072: ping-pong buffer offset
#define NTH 192
#define PLANE 16384         // floats per gate combo plane (128*128)

__device__ __forceinline__ float fast_sigmoid(float v) {
    return __builtin_amdgcn_rcpf(1.0f + __expf(-v));   // |rel err| ~1e-7, fine vs 1.4e-2
}

// Full 16-gate multilinear interp layer: st[src] -> st[dst] for this thread's cell.
// NOTE: no clamp — gates are sigmoids in (0,1) and state is multilinear in them,
// so the reference's clip() is a no-op to within the ~1e-7 sigmoid approx error.
__device__ __forceinline__ void compute_layer(float* __restrict__ st, int src, int dst,
                                              int sbase, const float g[16]) {
    float d[8];
#pragma unroll
    for (int k = 0; k < 8; ++k) d[k] = g[2 * k + 1] - g[2 * k];   // batch-invariant
#pragma unroll
    for (int b = 0; b < NBH; ++b) {
        const float* sb = st + src + b * BSTR + sbase;
        const float f0 = sb[0], f1 = sb[1], f2 = sb[RS], f3 = sb[RS + 1];
        float u[8];
#pragma unroll
        for (int k = 0; k < 8; ++k) u[k] = fmaf(f3, d[k], g[2 * k]);
        float v[4];
#pragma unroll
        for (int k = 0; k < 4; ++k) v[k] = fmaf(f2, u[2 * k + 1] - u[2 * k], u[2 * k]);
        float w[2];
#pragma unroll
        for (int k = 0; k < 2; ++k) w[k] = fmaf(f1, v[2 * k + 1] - v[2 * k], v[2 * k]);
        st[dst + b * BSTR + sbase] = fmaf(f0, w[1] - w[0], w[0]);
    }
}

__global__ __launch_bounds__(NTH) void fused_kernel(const float* __restrict__ x,
                                                    const float* __restrict__ tg,
                                                    float* __restrict__ out) {
    __shared__ float st[2 * B1 + 64];    // ping-pong state + pad for harmless edge reads

    const int tid  = threadIdx.x;
    const int tile = blockIdx.x & 255;
    const int b0   = (blockIdx.x >> 8) * NBH;    // batch offset of this half

    const int q1 = tid >> 4;             // 0..11
    const int q2 = tid & 15;             // 0..15
    const bool act = (q2 < RR);

    const int t1 = ((tile >> 4) & 15) << 3;
    const int t2 = (tile & 15) << 3;
    const int p1  = (t1 + q1) & (D1 - 1);
    const int p2  = (t2 + q2) & (D2 - 1);
    const int p1n = (p1 + 1) & (D1 - 1);
    const int p2n = (p2 + 1) & (D2 - 1);
    const int sbase = (q1 << 4) | q2;
    const int modd = p2 & 1;             // == q2&1 since t2 is even
    const float* gcell = tg + (p1 << 7) + p2;

    // ---- gate loads for layers 0 and 1 issued up front ----
    float g0[4], graw[16];
    if (act) {
        // layer-0 gates: parity-reduced bilerp needs only 4 of 16 combos
        // even p2 (f1=f3=0): m in {0,2,8,10};  odd p2 (f0=f2=0): m in {0,1,4,5}
#pragma unroll
        for (int j = 0; j < 4; ++j) {
            const int m = modd ? ((j >> 1) * 4 + (j & 1)) : ((j >> 1) * 8 + (j & 1) * 2);
            g0[j] = gcell[(size_t)m * PLANE];
        }
#pragma unroll
        for (int m = 0; m < 16; ++m) graw[m] = gcell[(size_t)(16 + m) * PLANE];
    }

    // ---- layer 0: read x DIRECTLY (no staging, no extra barrier) -> st[B1] ----
    // even cell: inner lerp over f2=x[p1n][c], outer over f0=x[p1][c]
    // odd  cell: inner lerp over f3=x[p1n][c], outer over f1=x[p1][c]
    if (act) {
#pragma unroll
        for (int j = 0; j < 4; ++j) g0[j] = fast_sigmoid(g0[j]);
        const float d10 = g0[1] - g0[0], d32 = g0[3] - g0[2];
        const int c = (modd ? p2n : p2) >> 1;
        const float* xo = x + ((size_t)b0 * D1 + p1)  * XC + c;   // outer tap
        const float* xi = x + ((size_t)b0 * D1 + p1n) * XC + c;   // inner tap
#pragma unroll
        for (int b = 0; b < NBH; ++b) {
            const float fout = xo[(size_t)b * (D1 * XC)];
            const float fin  = xi[(size_t)b * (D1 * XC)];
            const float a_ = fmaf(fin, d10, g0[0]);
            const float c_ = fmaf(fin, d32, g0[2]);
            st[B1 + b * BSTR + sbase] = fmaf(fout, c_ - a_, a_);
        }
    }
    __syncthreads();

    // ---- layer 1: st[B1] -> st[0]; prefetch layer-2 gates ----
    float g[16], graw2[16];
    if (act) {
#pragma unroll
        for (int m = 0; m < 16; ++m) graw2[m] = gcell[(size_t)(32 + m) * PLANE];
#pragma unroll
        for (int m = 0; m < 16; ++m) g[m] = fast_sigmoid(graw[m]);
        compute_layer(st, B1, 0, sbase, g);
    }
    __syncthreads();

    // ---- tail mapping: 32 cells x 4 batch-groups over 128 threads ----
    const int c1 = (tid >> 2) & 7;       // tail cell row 0..7
    const int c2 = tid & 3;              // tail even-col index 0..3
    const int bh = tid >> 5;             // batch group 0..3 (tid<128)
    const int p1c = t1 + c1;             // no wrap needed
    const int p2c = t2 + (c2 << 1);
    const float* gcell3 = tg + (size_t)48 * PLANE + (p1c << 7) + p2c;

    // ---- layer 2: st[0] -> st[B1]; prefetch layer-3 gates for tail cell ----
    float graw3[16];
    if (tid < 128) {
#pragma unroll
        for (int m = 0; m < 16; ++m) graw3[m] = gcell3[(size_t)m * PLANE];
    }
    if (act) {
#pragma unroll
        for (int m = 0; m < 16; ++m) g[m] = fast_sigmoid(graw2[m]);
        compute_layer(st, 0, B1, sbase, g);
    }
    __syncthreads();

    // ---- layer 3: each of 128 threads does its tail cell for 4 batches -> out ----
    if (tid < 128) {
#pragma unroll
        for (int m = 0; m < 16; ++m) g[m] = fast_sigmoid(graw3[m]);
        float d[8];
#pragma unroll
        for (int k = 0; k < 8; ++k) d[k] = g[2 * k + 1] - g[2 * k];
        const int sb3 = (c1 << 4) | (c2 << 1);
        float* op = out + ((size_t)(b0 + bh * 4) * D1 + p1c) * XC + (p2c >> 1);
#pragma unroll
        for (int b = 0; b < 4; ++b) {
            const float* sb = st + B1 + (bh * 4 + b) * BSTR + sb3;
            const float f0 = sb[0], f1 = sb[1], f2 = sb[RS], f3 = sb[RS + 1];
            float u[8];
#pragma unroll
            for (int k = 0; k < 8; ++k) u[k] = fmaf(f3, d[k], g[2 * k]);
            float v[4];
#pragma unroll
            for (int k = 0; k < 4; ++k) v[k] = fmaf(f2, u[2 * k + 1] - u[2 * k], u[2 * k]);
            float w[2];
#pragma unroll
            for (int k = 0; k < 2; ++k) w[k] = fmaf(f1, v[2 * k + 1] - v[2 * k], v[2 * k]);
            const float r = fmaf(f0, w[1] - w[0], w[0]);
            op[(size_t)b * (D1 * XC)] = fminf(fmaxf(r, 0.0f), 1.0f);  // exact output-range parity
        }
    }
}

extern "C" void kernel_launch(void* const* d_in, const int* in_sizes, int n_in,
                              void* d_out, int out_size, void* d_ws, size_t ws_size,
                              hipStream_t stream) {
    const float* x  = (const float*)d_in[0];   // (32,128,64)
    const float* tg = (const float*)d_in[1];   // (4,16,128,128)
    float* out = (float*)d_out;                // (32,128,64)

    fused_kernel<<<512, NTH, 0, stream>>>(x, tg, out);
}